// Round 5
// baseline (407.417 us; speedup 1.0000x reference)
//
#include <hip/hip_runtime.h>
#include <hip/hip_fp16.h>
#include <math.h>

constexpr int D = 128;

struct __align__(16) H8 { __half2 h[4]; };
struct __align__(8)  H4 { __half2 a, b; };

// ---------------- preprocessing ----------------

__device__ __forceinline__ int detect64(const int* __restrict__ ei) {
  int z = 0;
#pragma unroll
  for (int i = 0; i < 8; ++i) z |= ei[2 * i + 1];
  return (z == 0) ? 1 : 0;
}

__device__ __forceinline__ void load_edge(const int* __restrict__ ei, int e, int nE,
                                          int m64, int n, int& r, int& c) {
  if (m64) { r = ei[2 * (size_t)e]; c = ei[2 * ((size_t)nE + e)]; }
  else     { r = ei[(size_t)e];     c = ei[(size_t)nE + e]; }
  r = min(max(r, 0), n - 1);
  c = min(max(c, 0), n - 1);
}

__global__ void k_zero(int* __restrict__ cnt, int n) {
  int i = blockIdx.x * blockDim.x + threadIdx.x;
  if (i < n) cnt[i] = 0;
}

__global__ void k_pos(const int* __restrict__ ei, int* __restrict__ cnt,
                      int2* __restrict__ rc, int* __restrict__ pos, int nE, int n) {
  int e = blockIdx.x * blockDim.x + threadIdx.x;
  if (e >= nE) return;
  int m64 = detect64(ei);
  int r, c;
  load_edge(ei, e, nE, m64, n, r, c);
  rc[e] = make_int2(r, c);
  pos[e] = atomicAdd(&cnt[c], 1);
}

__global__ void k_scan1(const int* __restrict__ cnt, int* __restrict__ offs,
                        int* __restrict__ bsum, int n) {
  __shared__ int s[256];
  int t = threadIdx.x;
  int i = blockIdx.x * 256 + t;
  int v = (i < n) ? cnt[i] : 0;
  s[t] = v;
  __syncthreads();
  for (int off = 1; off < 256; off <<= 1) {
    int x = 0;
    if (t >= off) x = s[t - off];
    __syncthreads();
    if (t >= off) s[t] += x;
    __syncthreads();
  }
  if (i < n) offs[i] = s[t] - v;
  if (t == 255) bsum[blockIdx.x] = s[255];
}

__global__ void k_scan2(const int* __restrict__ bsum, int* __restrict__ boff, int nb) {
  __shared__ int s[256];
  int t = threadIdx.x;
  int v = (t < nb) ? bsum[t] : 0;
  s[t] = v;
  __syncthreads();
  for (int off = 1; off < 256; off <<= 1) {
    int x = 0;
    if (t >= off) x = s[t - off];
    __syncthreads();
    if (t >= off) s[t] += x;
    __syncthreads();
  }
  if (t < nb) boff[t] = s[t] - v;
}

__global__ void k_scan3(int* __restrict__ offs, const int* __restrict__ boff, int n, int nE) {
  int i = blockIdx.x * 256 + threadIdx.x;
  if (i < n) offs[i] += boff[blockIdx.x];
  if (i == 0) offs[n] = nE;
}

__global__ void k_fill(const int2* __restrict__ rc, const int* __restrict__ pos,
                       const float* __restrict__ w, const int* __restrict__ offs,
                       int2* __restrict__ ecf, int nE) {
  int e = blockIdx.x * blockDim.x + threadIdx.x;
  if (e >= nE) return;
  int2 p = rc[e];
  int idx = offs[p.y] + pos[e];
  ecf[idx] = make_int2(p.x, __float_as_int(w[e]));
}

__global__ void k_degdinv(const int2* __restrict__ ecf, const int* __restrict__ offs,
                          float* __restrict__ dinv, int n) {
  int i = blockIdx.x * blockDim.x + threadIdx.x;
  if (i >= n) return;
  float s = 1.0f;
  int e1 = offs[i + 1];
  for (int e = offs[i]; e < e1; ++e) s += __int_as_float(ecf[e].y);
  dinv[i] = rsqrtf(s);
}

// Pack edge -> (src<<16) | fp16(dinv[src]*w).  Requires n <= 65536 (N=50000).
__global__ void k_coef(const int2* __restrict__ ecf, const float* __restrict__ dinv,
                       unsigned int* __restrict__ ecf2, int nE) {
  int e = blockIdx.x * blockDim.x + threadIdx.x;
  if (e >= nE) return;
  int2 p = ecf[e];
  float c = dinv[p.x] * __int_as_float(p.y);
  ecf2[e] = ((unsigned int)p.x << 16) |
            (unsigned int)__half_as_ushort(__float2half_rn(c));
}

// ---------------- GEMM: Yc = half( act(A) @ W ), column-blocked output ----------------
// Yc layout: 16 regions of [n][8] halves; element (row, col) at
//   (col>>3)*n*8 + row*8 + (col&7).
template <int ACT>
__device__ __forceinline__ float act_f(float x) {
  if (ACT == 1) return x > 0.f ? x : expm1f(x);
  if (ACT == 2) return 0.5f * x * (1.0f + erff(x * 0.70710678118654752440f));
  return x;
}

template <int ACT, typename AT>
__global__ __launch_bounds__(256, 2) void k_gemm(const AT* __restrict__ A,
                                                 const float* __restrict__ W,
                                                 __half* __restrict__ Y, int n) {
  __shared__ float As[128 * 33];
  __shared__ float Ws[32 * 128];
  const int tid = threadIdx.x;
  const int row0 = blockIdx.x * 128;
  const int tc = tid & 15;
  const int tr = tid >> 4;

  float acc[8][8];
#pragma unroll
  for (int i = 0; i < 8; ++i)
#pragma unroll
    for (int j = 0; j < 8; ++j) acc[i][j] = 0.f;

  for (int kt = 0; kt < 4; ++kt) {
    // stage A tile (128 rows x 32 k), activation fused
    if constexpr (sizeof(AT) == 4) {
      // row-major fp32 input (layer 1)
#pragma unroll
      for (int i = 0; i < 4; ++i) {
        int idx = tid + i * 256;
        int r = idx >> 3;
        int c4 = idx & 7;
        float4 v = make_float4(0.f, 0.f, 0.f, 0.f);
        int gr = row0 + r;
        if (gr < n) v = *(const float4*)((const float*)A + (size_t)gr * D + kt * 32 + c4 * 4);
        As[r * 33 + c4 * 4 + 0] = act_f<ACT>(v.x);
        As[r * 33 + c4 * 4 + 1] = act_f<ACT>(v.y);
        As[r * 33 + c4 * 4 + 2] = act_f<ACT>(v.z);
        As[r * 33 + c4 * 4 + 3] = act_f<ACT>(v.w);
      }
    } else {
      // column-blocked fp16 input: region jc holds [n][8] halves
#pragma unroll
      for (int i = 0; i < 2; ++i) {
        int idx = tid + i * 256;          // 0..511
        int jcl = idx >> 7;               // 0..3 (chunk within this K-tile)
        int r = idx & 127;
        float f[8] = {0.f, 0.f, 0.f, 0.f, 0.f, 0.f, 0.f, 0.f};
        int gr = row0 + r;
        if (gr < n) {
          H8 v = *(const H8*)((const __half*)A + ((size_t)(kt * 4 + jcl) * n + gr) * 8);
#pragma unroll
          for (int t = 0; t < 4; ++t) {
            float2 p = __half22float2(v.h[t]);
            f[2 * t] = p.x; f[2 * t + 1] = p.y;
          }
        }
#pragma unroll
        for (int t = 0; t < 8; ++t)
          As[r * 33 + jcl * 8 + t] = act_f<ACT>(f[t]);
      }
    }
    // stage W tile (32 k x 128 cols)
#pragma unroll
    for (int i = 0; i < 4; ++i) {
      int idx = tid + i * 256;
      int r = idx >> 5;
      int c4 = idx & 31;
      *(float4*)(&Ws[r * 128 + c4 * 4]) =
          *(const float4*)(W + (size_t)(kt * 32 + r) * D + c4 * 4);
    }
    __syncthreads();
#pragma unroll
    for (int k = 0; k < 32; ++k) {
      float a[8];
#pragma unroll
      for (int i = 0; i < 8; ++i) a[i] = As[(tr * 8 + i) * 33 + k];
      const float4 b0 = *(const float4*)(&Ws[k * 128 + tc * 4]);
      const float4 b1 = *(const float4*)(&Ws[k * 128 + tc * 4 + 64]);
#pragma unroll
      for (int i = 0; i < 8; ++i) {
        acc[i][0] += a[i] * b0.x; acc[i][1] += a[i] * b0.y;
        acc[i][2] += a[i] * b0.z; acc[i][3] += a[i] * b0.w;
        acc[i][4] += a[i] * b1.x; acc[i][5] += a[i] * b1.y;
        acc[i][6] += a[i] * b1.z; acc[i][7] += a[i] * b1.w;
      }
    }
    __syncthreads();
  }
  // epilogue: cols tc*4..+3 -> region tc>>1 offset (tc&1)*4; cols +64 -> region 8+(tc>>1)
  const int jc0 = tc >> 1;
  const int off0 = (tc & 1) * 4;
#pragma unroll
  for (int i = 0; i < 8; ++i) {
    int gr = row0 + tr * 8 + i;
    if (gr < n) {
      H4 lo, hi;
      lo.a = __floats2half2_rn(acc[i][0], acc[i][1]);
      lo.b = __floats2half2_rn(acc[i][2], acc[i][3]);
      hi.a = __floats2half2_rn(acc[i][4], acc[i][5]);
      hi.b = __floats2half2_rn(acc[i][6], acc[i][7]);
      *(H4*)(Y + ((size_t)jc0 * n + gr) * 8 + off0) = lo;
      *(H4*)(Y + ((size_t)(8 + jc0) * n + gr) * 8 + off0) = hi;
    }
  }
}

// -------- aggregation (column-blocked): OUT[c] = dc*( sum coef*Yc[r] + dc*Yc[c] ) + b ----
// grid = 16 * nodeblocks; jc = blockIdx & 15 so XCD round-robin pins jc classes per XCD
// (per-XCD gather working set = 2 * N*16B = 1.6 MB, L2-resident).
__device__ __forceinline__ void fmacc8(float* acc, float c, const H8& y) {
  float2 f;
  f = __half22float2(y.h[0]); acc[0] += c * f.x; acc[1] += c * f.y;
  f = __half22float2(y.h[1]); acc[2] += c * f.x; acc[3] += c * f.y;
  f = __half22float2(y.h[2]); acc[4] += c * f.x; acc[5] += c * f.y;
  f = __half22float2(y.h[3]); acc[6] += c * f.x; acc[7] += c * f.y;
}

__device__ __forceinline__ float cdecode(unsigned int u) {
  return __half2float(__ushort_as_half((unsigned short)(u & 0xffffu)));
}

template <int PRELU, typename OutT>
__global__ __launch_bounds__(256) void k_agg(const __half* __restrict__ Y,
                                             const int* __restrict__ offs,
                                             const unsigned int* __restrict__ ecf2,
                                             const float* __restrict__ dinv,
                                             const float* __restrict__ bias,
                                             const float* __restrict__ pw,
                                             OutT* __restrict__ OUT, int n) {
  const int jc = blockIdx.x & 15;
  const int node = (blockIdx.x >> 4) * 256 + threadIdx.x;
  if (node >= n) return;
  const __half* Yj = Y + (size_t)jc * n * 8;
  float dc = dinv[node];
  float acc[8] = {0.f, 0.f, 0.f, 0.f, 0.f, 0.f, 0.f, 0.f};
  {
    H8 ys = *(const H8*)(Yj + (size_t)node * 8);
    fmacc8(acc, dc, ys);
  }
  int e0 = offs[node], e1 = offs[node + 1];
  int e = e0;
  for (; e + 4 <= e1; e += 4) {
    unsigned int u0 = ecf2[e], u1 = ecf2[e + 1], u2 = ecf2[e + 2], u3 = ecf2[e + 3];
    H8 y0 = *(const H8*)(Yj + (size_t)(u0 >> 16) * 8);
    H8 y1 = *(const H8*)(Yj + (size_t)(u1 >> 16) * 8);
    H8 y2 = *(const H8*)(Yj + (size_t)(u2 >> 16) * 8);
    H8 y3 = *(const H8*)(Yj + (size_t)(u3 >> 16) * 8);
    fmacc8(acc, cdecode(u0), y0);
    fmacc8(acc, cdecode(u1), y1);
    fmacc8(acc, cdecode(u2), y2);
    fmacc8(acc, cdecode(u3), y3);
  }
  for (; e < e1; ++e) {
    unsigned int u = ecf2[e];
    H8 y = *(const H8*)(Yj + (size_t)(u >> 16) * 8);
    fmacc8(acc, cdecode(u), y);
  }
  float4 b0 = *(const float4*)(bias + jc * 8);
  float4 b1 = *(const float4*)(bias + jc * 8 + 4);
  float o[8];
  o[0] = dc * acc[0] + b0.x; o[1] = dc * acc[1] + b0.y;
  o[2] = dc * acc[2] + b0.z; o[3] = dc * acc[3] + b0.w;
  o[4] = dc * acc[4] + b1.x; o[5] = dc * acc[5] + b1.y;
  o[6] = dc * acc[6] + b1.z; o[7] = dc * acc[7] + b1.w;
  if (PRELU) {
    float wv = *pw;
#pragma unroll
    for (int i = 0; i < 8; ++i) o[i] = o[i] >= 0.f ? o[i] : wv * o[i];
  }
  if constexpr (sizeof(OutT) == 2) {
    // column-blocked fp16 (feeds next GEMM)
    H8 hv;
    hv.h[0] = __floats2half2_rn(o[0], o[1]);
    hv.h[1] = __floats2half2_rn(o[2], o[3]);
    hv.h[2] = __floats2half2_rn(o[4], o[5]);
    hv.h[3] = __floats2half2_rn(o[6], o[7]);
    *(H8*)((__half*)OUT + ((size_t)jc * n + node) * 8) = hv;
  } else {
    // row-major fp32 final output
    *(float4*)((float*)OUT + (size_t)node * D + jc * 8)     = make_float4(o[0], o[1], o[2], o[3]);
    *(float4*)((float*)OUT + (size_t)node * D + jc * 8 + 4) = make_float4(o[4], o[5], o[6], o[7]);
  }
}

// ---------------- launch ----------------
extern "C" void kernel_launch(void* const* d_in, const int* in_sizes, int n_in,
                              void* d_out, int out_size, void* d_ws, size_t ws_size,
                              hipStream_t stream) {
  const float* x  = (const float*)d_in[0];
  const int*   ei = (const int*)d_in[1];
  const float* w  = (const float*)d_in[2];
  const float* W1 = (const float*)d_in[3];
  const float* b1 = (const float*)d_in[4];
  const float* W2 = (const float*)d_in[5];
  const float* b2 = (const float*)d_in[6];
  const float* W3 = (const float*)d_in[7];
  const float* b3 = (const float*)d_in[8];
  const float* pw = (const float*)d_in[9];
  const int N = in_sizes[0] / D;
  const int E = in_sizes[2];
  float* out = (float*)d_out;

  char* wsb = (char*)d_ws;
  size_t off = 0;
  auto alloc = [&](size_t bytes) {
    void* p = wsb + off;
    off = (off + bytes + 255) & ~(size_t)255;
    return p;
  };
  float*        dinv = (float*)alloc((size_t)N * 4);
  int*          cnt  = (int*)alloc((size_t)N * 4);
  int*          offs = (int*)alloc((size_t)(N + 1) * 4);
  int*          bsum = (int*)alloc(256 * 4);
  int*          boff = (int*)alloc(256 * 4);
  int2*         ecf  = (int2*)alloc((size_t)E * 8);
  unsigned int* ecf2 = (unsigned int*)alloc((size_t)E * 4);
  __half*       Y    = (__half*)alloc((size_t)N * D * 2);
  __half*       h    = (__half*)alloc((size_t)N * D * 2);
  // transient buffers aliased into Y (dead before first GEMM writes Y): 12B/edge < N*D*2
  int2*         rc   = (int2*)Y;
  int*          pos  = (int*)((char*)Y + (size_t)E * 8);

  const int nb = (N + 255) / 256;
  const int eb = (E + 255) / 256;

  hipLaunchKernelGGL(k_zero,    dim3(nb), dim3(256), 0, stream, cnt, N);
  hipLaunchKernelGGL(k_pos,     dim3(eb), dim3(256), 0, stream, ei, cnt, rc, pos, E, N);
  hipLaunchKernelGGL(k_scan1,   dim3(nb), dim3(256), 0, stream, cnt, offs, bsum, N);
  hipLaunchKernelGGL(k_scan2,   dim3(1),  dim3(256), 0, stream, bsum, boff, nb);
  hipLaunchKernelGGL(k_scan3,   dim3(nb), dim3(256), 0, stream, offs, boff, N, E);
  hipLaunchKernelGGL(k_fill,    dim3(eb), dim3(256), 0, stream, rc, pos, w, offs, ecf, E);
  hipLaunchKernelGGL(k_degdinv, dim3(nb), dim3(256), 0, stream, ecf, offs, dinv, N);
  hipLaunchKernelGGL(k_coef,    dim3(eb), dim3(256), 0, stream, ecf, dinv, ecf2, E);

  const int gb = (N + 127) / 128;
  const int ab = 16 * ((N + 255) / 256);

  hipLaunchKernelGGL((k_gemm<0, float>),  dim3(gb), dim3(256), 0, stream, x, W1, Y, N);
  hipLaunchKernelGGL((k_agg<0, __half>),  dim3(ab), dim3(256), 0, stream, Y, offs, ecf2, dinv, b1, pw, h, N);
  hipLaunchKernelGGL((k_gemm<1, __half>), dim3(gb), dim3(256), 0, stream, h, W2, Y, N);
  hipLaunchKernelGGL((k_agg<0, __half>),  dim3(ab), dim3(256), 0, stream, Y, offs, ecf2, dinv, b2, pw, h, N);
  hipLaunchKernelGGL((k_gemm<2, __half>), dim3(gb), dim3(256), 0, stream, h, W3, Y, N);
  hipLaunchKernelGGL((k_agg<1, float>),   dim3(ab), dim3(256), 0, stream, Y, offs, ecf2, dinv, b3, pw, out, N);
}

// Round 6
// 307.395 us; speedup vs baseline: 1.3254x; 1.3254x over previous
//
#include <hip/hip_runtime.h>
#include <hip/hip_fp16.h>
#include <math.h>

constexpr int D = 128;

struct __align__(16) H8 { __half2 h[4]; };
struct __align__(8)  H4 { __half2 a, b; };

typedef _Float16 half8 __attribute__((ext_vector_type(8)));
typedef float    floatx4 __attribute__((ext_vector_type(4)));

// ---------------- preprocessing ----------------

__device__ __forceinline__ int detect64(const int* __restrict__ ei) {
  int z = 0;
#pragma unroll
  for (int i = 0; i < 8; ++i) z |= ei[2 * i + 1];
  return (z == 0) ? 1 : 0;
}

__device__ __forceinline__ void load_edge(const int* __restrict__ ei, int e, int nE,
                                          int m64, int n, int& r, int& c) {
  if (m64) { r = ei[2 * (size_t)e]; c = ei[2 * ((size_t)nE + e)]; }
  else     { r = ei[(size_t)e];     c = ei[(size_t)nE + e]; }
  r = min(max(r, 0), n - 1);
  c = min(max(c, 0), n - 1);
}

__global__ void k_zero(int* __restrict__ cnt, int n) {
  int i = blockIdx.x * blockDim.x + threadIdx.x;
  if (i < n) cnt[i] = 0;
}

__global__ void k_pos(const int* __restrict__ ei, int* __restrict__ cnt,
                      int2* __restrict__ rc, int* __restrict__ pos, int nE, int n) {
  int e = blockIdx.x * blockDim.x + threadIdx.x;
  if (e >= nE) return;
  int m64 = detect64(ei);
  int r, c;
  load_edge(ei, e, nE, m64, n, r, c);
  rc[e] = make_int2(r, c);
  pos[e] = atomicAdd(&cnt[c], 1);
}

__global__ void k_scan1(const int* __restrict__ cnt, int* __restrict__ offs,
                        int* __restrict__ bsum, int n) {
  __shared__ int s[256];
  int t = threadIdx.x;
  int i = blockIdx.x * 256 + t;
  int v = (i < n) ? cnt[i] : 0;
  s[t] = v;
  __syncthreads();
  for (int off = 1; off < 256; off <<= 1) {
    int x = 0;
    if (t >= off) x = s[t - off];
    __syncthreads();
    if (t >= off) s[t] += x;
    __syncthreads();
  }
  if (i < n) offs[i] = s[t] - v;
  if (t == 255) bsum[blockIdx.x] = s[255];
}

__global__ void k_scan2(const int* __restrict__ bsum, int* __restrict__ boff, int nb) {
  __shared__ int s[256];
  int t = threadIdx.x;
  int v = (t < nb) ? bsum[t] : 0;
  s[t] = v;
  __syncthreads();
  for (int off = 1; off < 256; off <<= 1) {
    int x = 0;
    if (t >= off) x = s[t - off];
    __syncthreads();
    if (t >= off) s[t] += x;
    __syncthreads();
  }
  if (t < nb) boff[t] = s[t] - v;
}

__global__ void k_scan3(int* __restrict__ offs, const int* __restrict__ boff, int n, int nE) {
  int i = blockIdx.x * 256 + threadIdx.x;
  if (i < n) offs[i] += boff[blockIdx.x];
  if (i == 0) offs[n] = nE;
}

__global__ void k_fill(const int2* __restrict__ rc, const int* __restrict__ pos,
                       const float* __restrict__ w, const int* __restrict__ offs,
                       int2* __restrict__ ecf, int nE) {
  int e = blockIdx.x * blockDim.x + threadIdx.x;
  if (e >= nE) return;
  int2 p = rc[e];
  int idx = offs[p.y] + pos[e];
  ecf[idx] = make_int2(p.x, __float_as_int(w[e]));
}

__global__ void k_degdinv(const int2* __restrict__ ecf, const int* __restrict__ offs,
                          float* __restrict__ dinv, int n) {
  int i = blockIdx.x * blockDim.x + threadIdx.x;
  if (i >= n) return;
  float s = 1.0f;
  int e1 = offs[i + 1];
  for (int e = offs[i]; e < e1; ++e) s += __int_as_float(ecf[e].y);
  dinv[i] = rsqrtf(s);
}

// Pack edge -> (src<<16) | fp16(dinv[src]*w).  Requires n <= 65536 (N=50000).
__global__ void k_coef(const int2* __restrict__ ecf, const float* __restrict__ dinv,
                       unsigned int* __restrict__ ecf2, int nE) {
  int e = blockIdx.x * blockDim.x + threadIdx.x;
  if (e >= nE) return;
  int2 p = ecf[e];
  float c = dinv[p.x] * __int_as_float(p.y);
  ecf2[e] = ((unsigned int)p.x << 16) |
            (unsigned int)__half_as_ushort(__float2half_rn(c));
}

// Transpose W1/W2/W3 (fp32 [k][n]) -> Wt fp16 [n][k], one block per matrix.
__global__ void k_wt(const float* __restrict__ W1, const float* __restrict__ W2,
                     const float* __restrict__ W3, __half* __restrict__ Wt) {
  __shared__ float s[128][129];
  const float* W = blockIdx.x == 0 ? W1 : (blockIdx.x == 1 ? W2 : W3);
  __half* o = Wt + (size_t)blockIdx.x * D * D;
  int tid = threadIdx.x;
#pragma unroll
  for (int i = 0; i < 16; ++i) {
    int flat = i * 1024 + tid * 4;        // float4 index space
    int k = flat >> 7;
    int nn = flat & 127;
    float4 v = *(const float4*)(W + (size_t)k * D + nn);
    s[k][nn] = v.x; s[k][nn + 1] = v.y; s[k][nn + 2] = v.z; s[k][nn + 3] = v.w;
  }
  __syncthreads();
#pragma unroll
  for (int i = 0; i < 8; ++i) {
    int flat = i * 256 + tid;             // 0..2047
    int nn = flat >> 4;
    int k0 = (flat & 15) * 8;
    H8 hv;
#pragma unroll
    for (int t = 0; t < 4; ++t)
      hv.h[t] = __floats2half2_rn(s[k0 + 2 * t][nn], s[k0 + 2 * t + 1][nn]);
    *(H8*)(o + (size_t)nn * D + k0) = hv;
  }
}

// ---------------- MFMA GEMM: Y = half( act(A) @ W ), via Wt = W^T fp16 ----------------
// Per wave: 16 nodes x 128 output features. A-operand = Wt rows (features),
// B-operand = act(node rows). D: col(lane&15)=node, row(quad*4+reg)=feature.
template <int ACT>
__device__ __forceinline__ float act_f(float x) {
  if (ACT == 1) return x > 0.f ? x : expm1f(x);
  if (ACT == 2) return 0.5f * x * (1.0f + erff(x * 0.70710678118654752440f));
  return x;
}

template <int ACT, typename AT>
__global__ __launch_bounds__(256) void k_gemm(const AT* __restrict__ A,
                                              const __half* __restrict__ Wt,
                                              __half* __restrict__ Y, int n) {
  const int wave = threadIdx.x >> 6;
  const int lane = threadIdx.x & 63;
  const int np = lane & 15;
  const int quad = lane >> 4;
  const int node = blockIdx.x * 64 + wave * 16 + np;
  const int nc = min(node, n - 1);

  // B-operand frags: b[s] = act(A[node][s*32 + quad*8 .. +7]) as fp16
  half8 b[4];
#pragma unroll
  for (int s = 0; s < 4; ++s) {
    if constexpr (sizeof(AT) == 4) {
      const float* ap = (const float*)A + (size_t)nc * D + s * 32 + quad * 8;
      float4 v0 = *(const float4*)ap;
      float4 v1 = *(const float4*)(ap + 4);
      b[s][0] = (_Float16)act_f<ACT>(v0.x); b[s][1] = (_Float16)act_f<ACT>(v0.y);
      b[s][2] = (_Float16)act_f<ACT>(v0.z); b[s][3] = (_Float16)act_f<ACT>(v0.w);
      b[s][4] = (_Float16)act_f<ACT>(v1.x); b[s][5] = (_Float16)act_f<ACT>(v1.y);
      b[s][6] = (_Float16)act_f<ACT>(v1.z); b[s][7] = (_Float16)act_f<ACT>(v1.w);
    } else {
      half8 raw = *(const half8*)((const __half*)A + (size_t)nc * D + s * 32 + quad * 8);
#pragma unroll
      for (int t = 0; t < 8; ++t)
        b[s][t] = (_Float16)act_f<ACT>((float)raw[t]);
    }
  }

  floatx4 acc[8];
#pragma unroll
  for (int mt = 0; mt < 8; ++mt) acc[mt] = (floatx4){0.f, 0.f, 0.f, 0.f};

#pragma unroll
  for (int mt = 0; mt < 8; ++mt) {
#pragma unroll
    for (int s = 0; s < 4; ++s) {
      half8 a = *(const half8*)(Wt + (size_t)(mt * 16 + np) * D + s * 32 + quad * 8);
      acc[mt] = __builtin_amdgcn_mfma_f32_16x16x32_f16(a, b[s], acc[mt], 0, 0, 0);
    }
  }

  if (node < n) {
#pragma unroll
    for (int mt = 0; mt < 8; ++mt) {
      H4 hv;
      hv.a = __floats2half2_rn(acc[mt][0], acc[mt][1]);
      hv.b = __floats2half2_rn(acc[mt][2], acc[mt][3]);
      *(H4*)(Y + (size_t)node * D + mt * 16 + quad * 4) = hv;
    }
  }
}

// -------- aggregation: OUT[c] = dc*( sum coef*Yh[r] + dc*Yh[c] ) + b --------
// 32 lanes per node: 2 edge-half-groups x 16 j-lanes (16B of the row each).
__device__ __forceinline__ void fmacc8(float* acc, float c, const H8& y) {
  float2 f;
  f = __half22float2(y.h[0]); acc[0] += c * f.x; acc[1] += c * f.y;
  f = __half22float2(y.h[1]); acc[2] += c * f.x; acc[3] += c * f.y;
  f = __half22float2(y.h[2]); acc[4] += c * f.x; acc[5] += c * f.y;
  f = __half22float2(y.h[3]); acc[6] += c * f.x; acc[7] += c * f.y;
}

__device__ __forceinline__ float cdecode(unsigned int u) {
  return __half2float(__ushort_as_half((unsigned short)(u & 0xffffu)));
}

template <int PRELU, typename OutT>
__global__ __launch_bounds__(256) void k_agg(const __half* __restrict__ Y,
                                             const int* __restrict__ offs,
                                             const unsigned int* __restrict__ ecf2,
                                             const float* __restrict__ dinv,
                                             const float* __restrict__ bias,
                                             const float* __restrict__ pw,
                                             OutT* __restrict__ OUT, int n) {
  int gi = blockIdx.x * blockDim.x + threadIdx.x;
  int node = gi >> 5;          // 32 lanes per node
  int sub = (gi >> 4) & 1;     // edge half-group
  int j = gi & 15;             // 8-half chunk (16B) of the 128-wide row
  if (node >= n) return;
  float dc = dinv[node];
  float acc[8] = {0.f, 0.f, 0.f, 0.f, 0.f, 0.f, 0.f, 0.f};
  if (sub == 0) {
    H8 ys = *(const H8*)(Y + (size_t)node * D + j * 8);
    fmacc8(acc, dc, ys);
  }
  int e0 = offs[node], e1 = offs[node + 1];
  int e = e0 + sub;
  for (; e + 6 < e1; e += 8) {   // this sub handles e, e+2, e+4, e+6
    unsigned int u0 = ecf2[e], u1 = ecf2[e + 2], u2 = ecf2[e + 4], u3 = ecf2[e + 6];
    H8 y0 = *(const H8*)(Y + (size_t)(u0 >> 16) * D + j * 8);
    H8 y1 = *(const H8*)(Y + (size_t)(u1 >> 16) * D + j * 8);
    H8 y2 = *(const H8*)(Y + (size_t)(u2 >> 16) * D + j * 8);
    H8 y3 = *(const H8*)(Y + (size_t)(u3 >> 16) * D + j * 8);
    fmacc8(acc, cdecode(u0), y0);
    fmacc8(acc, cdecode(u1), y1);
    fmacc8(acc, cdecode(u2), y2);
    fmacc8(acc, cdecode(u3), y3);
  }
  for (; e < e1; e += 2) {
    unsigned int u = ecf2[e];
    H8 y = *(const H8*)(Y + (size_t)(u >> 16) * D + j * 8);
    fmacc8(acc, cdecode(u), y);
  }
  // combine the two halves (xor lane 16 within the 32-lane node group)
#pragma unroll
  for (int i = 0; i < 8; ++i) acc[i] += __shfl_xor(acc[i], 16, 64);
  // each sub writes its own 16B: elements j*8 + sub*4 .. +3
  float4 b4 = *(const float4*)(bias + j * 8 + sub * 4);
  float o[4];
  o[0] = dc * acc[sub * 4 + 0] + b4.x;
  o[1] = dc * acc[sub * 4 + 1] + b4.y;
  o[2] = dc * acc[sub * 4 + 2] + b4.z;
  o[3] = dc * acc[sub * 4 + 3] + b4.w;
  if (PRELU) {
    float wv = *pw;
#pragma unroll
    for (int i = 0; i < 4; ++i) o[i] = o[i] >= 0.f ? o[i] : wv * o[i];
  }
  if constexpr (sizeof(OutT) == 4) {
    *(float4*)((float*)OUT + (size_t)node * D + j * 8 + sub * 4) =
        make_float4(o[0], o[1], o[2], o[3]);
  } else {
    H4 hv;
    hv.a = __floats2half2_rn(o[0], o[1]);
    hv.b = __floats2half2_rn(o[2], o[3]);
    *(H4*)((__half*)OUT + (size_t)node * D + j * 8 + sub * 4) = hv;
  }
}

// ---------------- launch ----------------
extern "C" void kernel_launch(void* const* d_in, const int* in_sizes, int n_in,
                              void* d_out, int out_size, void* d_ws, size_t ws_size,
                              hipStream_t stream) {
  const float* x  = (const float*)d_in[0];
  const int*   ei = (const int*)d_in[1];
  const float* w  = (const float*)d_in[2];
  const float* W1 = (const float*)d_in[3];
  const float* b1 = (const float*)d_in[4];
  const float* W2 = (const float*)d_in[5];
  const float* b2 = (const float*)d_in[6];
  const float* W3 = (const float*)d_in[7];
  const float* b3 = (const float*)d_in[8];
  const float* pw = (const float*)d_in[9];
  const int N = in_sizes[0] / D;
  const int E = in_sizes[2];
  float* out = (float*)d_out;

  char* wsb = (char*)d_ws;
  size_t off = 0;
  auto alloc = [&](size_t bytes) {
    void* p = wsb + off;
    off = (off + bytes + 255) & ~(size_t)255;
    return p;
  };
  float*        dinv = (float*)alloc((size_t)N * 4);
  int*          cnt  = (int*)alloc((size_t)N * 4);
  int*          offs = (int*)alloc((size_t)(N + 1) * 4);
  int*          bsum = (int*)alloc(256 * 4);
  int*          boff = (int*)alloc(256 * 4);
  int2*         ecf  = (int2*)alloc((size_t)E * 8);
  unsigned int* ecf2 = (unsigned int*)alloc((size_t)E * 4);
  __half*       Wt   = (__half*)alloc((size_t)3 * D * D * 2);
  __half*       Y    = (__half*)alloc((size_t)N * D * 2);
  __half*       h    = (__half*)alloc((size_t)N * D * 2);
  // transient buffers aliased into Y (dead before first GEMM writes Y): 12B/edge < N*D*2
  int2*         rc   = (int2*)Y;
  int*          pos  = (int*)((char*)Y + (size_t)E * 8);

  const int nb = (N + 255) / 256;
  const int eb = (E + 255) / 256;

  hipLaunchKernelGGL(k_wt,      dim3(3),  dim3(256), 0, stream, W1, W2, W3, Wt);
  hipLaunchKernelGGL(k_zero,    dim3(nb), dim3(256), 0, stream, cnt, N);
  hipLaunchKernelGGL(k_pos,     dim3(eb), dim3(256), 0, stream, ei, cnt, rc, pos, E, N);
  hipLaunchKernelGGL(k_scan1,   dim3(nb), dim3(256), 0, stream, cnt, offs, bsum, N);
  hipLaunchKernelGGL(k_scan2,   dim3(1),  dim3(256), 0, stream, bsum, boff, nb);
  hipLaunchKernelGGL(k_scan3,   dim3(nb), dim3(256), 0, stream, offs, boff, N, E);
  hipLaunchKernelGGL(k_fill,    dim3(eb), dim3(256), 0, stream, rc, pos, w, offs, ecf, E);
  hipLaunchKernelGGL(k_degdinv, dim3(nb), dim3(256), 0, stream, ecf, offs, dinv, N);
  hipLaunchKernelGGL(k_coef,    dim3(eb), dim3(256), 0, stream, ecf, dinv, ecf2, E);

  const int gb = (N + 63) / 64;
  const int ab = (N * 32 + 255) / 256;

  hipLaunchKernelGGL((k_gemm<0, float>),  dim3(gb), dim3(256), 0, stream, x, Wt,             Y, N);
  hipLaunchKernelGGL((k_agg<0, __half>),  dim3(ab), dim3(256), 0, stream, Y, offs, ecf2, dinv, b1, pw, h, N);
  hipLaunchKernelGGL((k_gemm<1, __half>), dim3(gb), dim3(256), 0, stream, h, Wt + D * D,     Y, N);
  hipLaunchKernelGGL((k_agg<0, __half>),  dim3(ab), dim3(256), 0, stream, Y, offs, ecf2, dinv, b2, pw, h, N);
  hipLaunchKernelGGL((k_gemm<2, __half>), dim3(gb), dim3(256), 0, stream, h, Wt + 2 * D * D, Y, N);
  hipLaunchKernelGGL((k_agg<1, float>),   dim3(ab), dim3(256), 0, stream, Y, offs, ecf2, dinv, b3, pw, out, N);
}

// Round 7
// 300.514 us; speedup vs baseline: 1.3557x; 1.0229x over previous
//
#include <hip/hip_runtime.h>
#include <hip/hip_fp16.h>
#include <math.h>

constexpr int D = 128;

struct __align__(16) H8 { __half2 h[4]; };
struct __align__(8)  H4 { __half2 a, b; };

typedef _Float16 half8 __attribute__((ext_vector_type(8)));
typedef float    floatx4 __attribute__((ext_vector_type(4)));

// ---------------- preprocessing ----------------

__device__ __forceinline__ int detect64(const int* __restrict__ ei) {
  int z = 0;
#pragma unroll
  for (int i = 0; i < 8; ++i) z |= ei[2 * i + 1];
  return (z == 0) ? 1 : 0;
}

__device__ __forceinline__ void load_edge(const int* __restrict__ ei, int e, int nE,
                                          int m64, int n, int& r, int& c) {
  if (m64) { r = ei[2 * (size_t)e]; c = ei[2 * ((size_t)nE + e)]; }
  else     { r = ei[(size_t)e];     c = ei[(size_t)nE + e]; }
  r = min(max(r, 0), n - 1);
  c = min(max(c, 0), n - 1);
}

__global__ void k_zero(int* __restrict__ cnt, int n) {
  int i = blockIdx.x * blockDim.x + threadIdx.x;
  if (i < n) cnt[i] = 0;
}

__global__ void k_pos(const int* __restrict__ ei, int* __restrict__ cnt,
                      int2* __restrict__ rc, int* __restrict__ pos, int nE, int n) {
  int e = blockIdx.x * blockDim.x + threadIdx.x;
  if (e >= nE) return;
  int m64 = detect64(ei);
  int r, c;
  load_edge(ei, e, nE, m64, n, r, c);
  rc[e] = make_int2(r, c);
  pos[e] = atomicAdd(&cnt[c], 1);
}

__global__ void k_scan1(const int* __restrict__ cnt, int* __restrict__ offs,
                        int* __restrict__ bsum, int n) {
  __shared__ int s[256];
  int t = threadIdx.x;
  int i = blockIdx.x * 256 + t;
  int v = (i < n) ? cnt[i] : 0;
  s[t] = v;
  __syncthreads();
  for (int off = 1; off < 256; off <<= 1) {
    int x = 0;
    if (t >= off) x = s[t - off];
    __syncthreads();
    if (t >= off) s[t] += x;
    __syncthreads();
  }
  if (i < n) offs[i] = s[t] - v;
  if (t == 255) bsum[blockIdx.x] = s[255];
}

__global__ void k_scan2(const int* __restrict__ bsum, int* __restrict__ boff, int nb) {
  __shared__ int s[256];
  int t = threadIdx.x;
  int v = (t < nb) ? bsum[t] : 0;
  s[t] = v;
  __syncthreads();
  for (int off = 1; off < 256; off <<= 1) {
    int x = 0;
    if (t >= off) x = s[t - off];
    __syncthreads();
    if (t >= off) s[t] += x;
    __syncthreads();
  }
  if (t < nb) boff[t] = s[t] - v;
}

__global__ void k_scan3(int* __restrict__ offs, const int* __restrict__ boff, int n, int nE) {
  int i = blockIdx.x * 256 + threadIdx.x;
  if (i < n) offs[i] += boff[blockIdx.x];
  if (i == 0) offs[n] = nE;
}

__global__ void k_fill(const int2* __restrict__ rc, const int* __restrict__ pos,
                       const float* __restrict__ w, const int* __restrict__ offs,
                       int2* __restrict__ ecf, int nE) {
  int e = blockIdx.x * blockDim.x + threadIdx.x;
  if (e >= nE) return;
  int2 p = rc[e];
  int idx = offs[p.y] + pos[e];
  ecf[idx] = make_int2(p.x, __float_as_int(w[e]));
}

__global__ void k_degdinv(const int2* __restrict__ ecf, const int* __restrict__ offs,
                          float* __restrict__ dinv, int n) {
  int i = blockIdx.x * blockDim.x + threadIdx.x;
  if (i >= n) return;
  float s = 1.0f;
  int e1 = offs[i + 1];
  for (int e = offs[i]; e < e1; ++e) s += __int_as_float(ecf[e].y);
  dinv[i] = rsqrtf(s);
}

// Pack edge -> (src<<16) | fp16(dinv[src]*w).  Requires n <= 65536 (N=50000).
__global__ void k_coef(const int2* __restrict__ ecf, const float* __restrict__ dinv,
                       unsigned int* __restrict__ ecf2, int nE) {
  int e = blockIdx.x * blockDim.x + threadIdx.x;
  if (e >= nE) return;
  int2 p = ecf[e];
  float c = dinv[p.x] * __int_as_float(p.y);
  ecf2[e] = ((unsigned int)p.x << 16) |
            (unsigned int)__half_as_ushort(__float2half_rn(c));
}

// Transpose W1/W2/W3 (fp32 [k][n]) -> Wt fp16 [n][k], one block per matrix.
__global__ void k_wt(const float* __restrict__ W1, const float* __restrict__ W2,
                     const float* __restrict__ W3, __half* __restrict__ Wt) {
  __shared__ float s[128][129];
  const float* W = blockIdx.x == 0 ? W1 : (blockIdx.x == 1 ? W2 : W3);
  __half* o = Wt + (size_t)blockIdx.x * D * D;
  int tid = threadIdx.x;
#pragma unroll
  for (int i = 0; i < 16; ++i) {
    int flat = i * 1024 + tid * 4;
    int k = flat >> 7;
    int nn = flat & 127;
    float4 v = *(const float4*)(W + (size_t)k * D + nn);
    s[k][nn] = v.x; s[k][nn + 1] = v.y; s[k][nn + 2] = v.z; s[k][nn + 3] = v.w;
  }
  __syncthreads();
#pragma unroll
  for (int i = 0; i < 8; ++i) {
    int flat = i * 256 + tid;
    int nn = flat >> 4;
    int k0 = (flat & 15) * 8;
    H8 hv;
#pragma unroll
    for (int t = 0; t < 4; ++t)
      hv.h[t] = __floats2half2_rn(s[k0 + 2 * t][nn], s[k0 + 2 * t + 1][nn]);
    *(H8*)(o + (size_t)nn * D + k0) = hv;
  }
}

// ---------------- MFMA GEMM: Y(chunk layout) = half( act(A) @ W ) ----------------
// Y layout: Y[chunk][n][32] halves, chunk = feature>>5.
template <int ACT>
__device__ __forceinline__ float act_f(float x) {
  if (ACT == 1) return x > 0.f ? x : expm1f(x);
  if (ACT == 2) return 0.5f * x * (1.0f + erff(x * 0.70710678118654752440f));
  return x;
}

template <int ACT, typename AT>
__global__ __launch_bounds__(256) void k_gemm(const AT* __restrict__ A,
                                              const __half* __restrict__ Wt,
                                              __half* __restrict__ Y, int n) {
  const int wave = threadIdx.x >> 6;
  const int lane = threadIdx.x & 63;
  const int np = lane & 15;
  const int quad = lane >> 4;
  const int node = blockIdx.x * 64 + wave * 16 + np;
  const int nc = min(node, n - 1);

  // B-operand frags: b[s] = act(A[node][s*32 + quad*8 .. +7]) as fp16
  half8 b[4];
#pragma unroll
  for (int s = 0; s < 4; ++s) {
    if constexpr (sizeof(AT) == 4) {
      const float* ap = (const float*)A + (size_t)nc * D + s * 32 + quad * 8;
      float4 v0 = *(const float4*)ap;
      float4 v1 = *(const float4*)(ap + 4);
      b[s][0] = (_Float16)act_f<ACT>(v0.x); b[s][1] = (_Float16)act_f<ACT>(v0.y);
      b[s][2] = (_Float16)act_f<ACT>(v0.z); b[s][3] = (_Float16)act_f<ACT>(v0.w);
      b[s][4] = (_Float16)act_f<ACT>(v1.x); b[s][5] = (_Float16)act_f<ACT>(v1.y);
      b[s][6] = (_Float16)act_f<ACT>(v1.z); b[s][7] = (_Float16)act_f<ACT>(v1.w);
    } else {
      // chunk layout: chunk s, node nc, halves quad*8..+7
      half8 raw = *(const half8*)((const __half*)A + ((size_t)s * n + nc) * 32 + quad * 8);
#pragma unroll
      for (int t = 0; t < 8; ++t)
        b[s][t] = (_Float16)act_f<ACT>((float)raw[t]);
    }
  }

  floatx4 acc[8];
#pragma unroll
  for (int mt = 0; mt < 8; ++mt) acc[mt] = (floatx4){0.f, 0.f, 0.f, 0.f};

#pragma unroll
  for (int mt = 0; mt < 8; ++mt) {
#pragma unroll
    for (int s = 0; s < 4; ++s) {
      half8 a = *(const half8*)(Wt + (size_t)(mt * 16 + np) * D + s * 32 + quad * 8);
      acc[mt] = __builtin_amdgcn_mfma_f32_16x16x32_f16(a, b[s], acc[mt], 0, 0, 0);
    }
  }

  if (node < n) {
#pragma unroll
    for (int mt = 0; mt < 8; ++mt) {
      H4 hv;
      hv.a = __floats2half2_rn(acc[mt][0], acc[mt][1]);
      hv.b = __floats2half2_rn(acc[mt][2], acc[mt][3]);
      int f0 = mt * 16 + quad * 4;
      *(H4*)(Y + ((size_t)(f0 >> 5) * n + node) * 32 + (f0 & 31)) = hv;
    }
  }
}

// -------- aggregation (chunked): per chunk c, OUT[:,c*32..] = dc*(sum coef*Yc[r] + dc*Yc[node]) + b
// node-group = 8 lanes: 2 edge-subs x 4 j-lanes (16B each) => one 64B line per edge gather.
// chunk = blockIdx & 3 so round-robin block->XCD pins chunk classes per XCD
// (per-XCD gather working set = 2 * N*64B = 6.4... -> chunks {c, c+4 absent}: 3.2MB/chunk, 2 classes/XCD).
__device__ __forceinline__ void fmacc8(float* acc, float c, const H8& y) {
  float2 f;
  f = __half22float2(y.h[0]); acc[0] += c * f.x; acc[1] += c * f.y;
  f = __half22float2(y.h[1]); acc[2] += c * f.x; acc[3] += c * f.y;
  f = __half22float2(y.h[2]); acc[4] += c * f.x; acc[5] += c * f.y;
  f = __half22float2(y.h[3]); acc[6] += c * f.x; acc[7] += c * f.y;
}

__device__ __forceinline__ float cdecode(unsigned int u) {
  return __half2float(__ushort_as_half((unsigned short)(u & 0xffffu)));
}

template <int PRELU, typename OutT>
__global__ __launch_bounds__(256) void k_agg(const __half* __restrict__ Y,
                                             const int* __restrict__ offs,
                                             const unsigned int* __restrict__ ecf2,
                                             const float* __restrict__ dinv,
                                             const float* __restrict__ bias,
                                             const float* __restrict__ pw,
                                             OutT* __restrict__ OUT, int n) {
  const int chunk = blockIdx.x & 3;
  const int t = threadIdx.x;
  const int node = (blockIdx.x >> 2) * 32 + (t >> 3);
  const int sub = (t >> 2) & 1;   // edge half-group
  const int j = t & 3;            // 16B piece of the 64B chunk
  if (node >= n) return;
  const __half* Yc = Y + (size_t)chunk * n * 32;
  float dc = dinv[node];
  float acc[8] = {0.f, 0.f, 0.f, 0.f, 0.f, 0.f, 0.f, 0.f};
  if (sub == 0) {
    H8 ys = *(const H8*)(Yc + (size_t)node * 32 + j * 8);
    fmacc8(acc, dc, ys);
  }
  int e0 = offs[node], e1 = offs[node + 1];
  int e = e0 + sub;
  for (; e + 6 < e1; e += 8) {   // this sub handles e, e+2, e+4, e+6
    unsigned int u0 = ecf2[e], u1 = ecf2[e + 2], u2 = ecf2[e + 4], u3 = ecf2[e + 6];
    H8 y0 = *(const H8*)(Yc + (size_t)(u0 >> 16) * 32 + j * 8);
    H8 y1 = *(const H8*)(Yc + (size_t)(u1 >> 16) * 32 + j * 8);
    H8 y2 = *(const H8*)(Yc + (size_t)(u2 >> 16) * 32 + j * 8);
    H8 y3 = *(const H8*)(Yc + (size_t)(u3 >> 16) * 32 + j * 8);
    fmacc8(acc, cdecode(u0), y0);
    fmacc8(acc, cdecode(u1), y1);
    fmacc8(acc, cdecode(u2), y2);
    fmacc8(acc, cdecode(u3), y3);
  }
  for (; e < e1; e += 2) {
    unsigned int u = ecf2[e];
    H8 y = *(const H8*)(Yc + (size_t)(u >> 16) * 32 + j * 8);
    fmacc8(acc, cdecode(u), y);
  }
  // combine the two subs (lanes differ in bit 2)
#pragma unroll
  for (int i = 0; i < 8; ++i) acc[i] += __shfl_xor(acc[i], 4, 64);
  // each sub writes its own 16B: features chunk*32 + j*8 + sub*4 .. +3
  float4 b4 = *(const float4*)(bias + chunk * 32 + j * 8 + sub * 4);
  float o[4];
  o[0] = dc * acc[sub * 4 + 0] + b4.x;
  o[1] = dc * acc[sub * 4 + 1] + b4.y;
  o[2] = dc * acc[sub * 4 + 2] + b4.z;
  o[3] = dc * acc[sub * 4 + 3] + b4.w;
  if (PRELU) {
    float wv = *pw;
#pragma unroll
    for (int i = 0; i < 4; ++i) o[i] = o[i] >= 0.f ? o[i] : wv * o[i];
  }
  if constexpr (sizeof(OutT) == 4) {
    // row-major fp32 final output
    *(float4*)((float*)OUT + (size_t)node * D + chunk * 32 + j * 8 + sub * 4) =
        make_float4(o[0], o[1], o[2], o[3]);
  } else {
    // chunk-layout fp16 (feeds next GEMM)
    H4 hv;
    hv.a = __floats2half2_rn(o[0], o[1]);
    hv.b = __floats2half2_rn(o[2], o[3]);
    *(H4*)((__half*)OUT + ((size_t)chunk * n + node) * 32 + j * 8 + sub * 4) = hv;
  }
}

// ---------------- launch ----------------
extern "C" void kernel_launch(void* const* d_in, const int* in_sizes, int n_in,
                              void* d_out, int out_size, void* d_ws, size_t ws_size,
                              hipStream_t stream) {
  const float* x  = (const float*)d_in[0];
  const int*   ei = (const int*)d_in[1];
  const float* w  = (const float*)d_in[2];
  const float* W1 = (const float*)d_in[3];
  const float* b1 = (const float*)d_in[4];
  const float* W2 = (const float*)d_in[5];
  const float* b2 = (const float*)d_in[6];
  const float* W3 = (const float*)d_in[7];
  const float* b3 = (const float*)d_in[8];
  const float* pw = (const float*)d_in[9];
  const int N = in_sizes[0] / D;
  const int E = in_sizes[2];
  float* out = (float*)d_out;

  char* wsb = (char*)d_ws;
  size_t off = 0;
  auto alloc = [&](size_t bytes) {
    void* p = wsb + off;
    off = (off + bytes + 255) & ~(size_t)255;
    return p;
  };
  float*        dinv = (float*)alloc((size_t)N * 4);
  int*          cnt  = (int*)alloc((size_t)N * 4);
  int*          offs = (int*)alloc((size_t)(N + 1) * 4);
  int*          bsum = (int*)alloc(256 * 4);
  int*          boff = (int*)alloc(256 * 4);
  int2*         ecf  = (int2*)alloc((size_t)E * 8);
  unsigned int* ecf2 = (unsigned int*)alloc((size_t)E * 4);
  __half*       Wt   = (__half*)alloc((size_t)3 * D * D * 2);
  __half*       Y    = (__half*)alloc((size_t)N * D * 2);
  __half*       h    = (__half*)alloc((size_t)N * D * 2);
  // transient buffers aliased into Y (dead before first GEMM writes Y): 12B/edge < N*D*2
  int2*         rc   = (int2*)Y;
  int*          pos  = (int*)((char*)Y + (size_t)E * 8);

  const int nb = (N + 255) / 256;
  const int eb = (E + 255) / 256;

  hipLaunchKernelGGL(k_wt,      dim3(3),  dim3(256), 0, stream, W1, W2, W3, Wt);
  hipLaunchKernelGGL(k_zero,    dim3(nb), dim3(256), 0, stream, cnt, N);
  hipLaunchKernelGGL(k_pos,     dim3(eb), dim3(256), 0, stream, ei, cnt, rc, pos, E, N);
  hipLaunchKernelGGL(k_scan1,   dim3(nb), dim3(256), 0, stream, cnt, offs, bsum, N);
  hipLaunchKernelGGL(k_scan2,   dim3(1),  dim3(256), 0, stream, bsum, boff, nb);
  hipLaunchKernelGGL(k_scan3,   dim3(nb), dim3(256), 0, stream, offs, boff, N, E);
  hipLaunchKernelGGL(k_fill,    dim3(eb), dim3(256), 0, stream, rc, pos, w, offs, ecf, E);
  hipLaunchKernelGGL(k_degdinv, dim3(nb), dim3(256), 0, stream, ecf, offs, dinv, N);
  hipLaunchKernelGGL(k_coef,    dim3(eb), dim3(256), 0, stream, ecf, dinv, ecf2, E);

  const int gb = (N + 63) / 64;
  const int ab = 4 * ((N + 31) / 32);

  hipLaunchKernelGGL((k_gemm<0, float>),  dim3(gb), dim3(256), 0, stream, x, Wt,             Y, N);
  hipLaunchKernelGGL((k_agg<0, __half>),  dim3(ab), dim3(256), 0, stream, Y, offs, ecf2, dinv, b1, pw, h, N);
  hipLaunchKernelGGL((k_gemm<1, __half>), dim3(gb), dim3(256), 0, stream, h, Wt + D * D,     Y, N);
  hipLaunchKernelGGL((k_agg<0, __half>),  dim3(ab), dim3(256), 0, stream, Y, offs, ecf2, dinv, b2, pw, h, N);
  hipLaunchKernelGGL((k_gemm<2, __half>), dim3(gb), dim3(256), 0, stream, h, Wt + 2 * D * D, Y, N);
  hipLaunchKernelGGL((k_agg<1, float>),   dim3(ab), dim3(256), 0, stream, Y, offs, ecf2, dinv, b3, pw, out, N);
}